// Round 1
// baseline (255.788 us; speedup 1.0000x reference)
//
#include <hip/hip_runtime.h>
#include <cstdint>
#include <cstddef>

// CrossMultiheadAttention: B=2, S=2048, E=1024, NHEAD=16, HEAD=64
// Pipeline: cast fp32->bf16 -> MFMA QKV projection (V stored transposed)
//           -> flash attention (online softmax) -> fp32 out.

using bf16 = __bf16;
typedef __bf16 bf16x8 __attribute__((ext_vector_type(8)));
typedef float f32x4 __attribute__((ext_vector_type(4)));

// async global->LDS, 16B per lane. LDS dest = wave-uniform base + lane*16.
__device__ __forceinline__ void async16(void* lds, const void* g) {
  __builtin_amdgcn_global_load_lds((__attribute__((address_space(1))) void*)g,
                                   (__attribute__((address_space(3))) void*)lds,
                                   16, 0, 0);
}

// ---------------------------------------------------------------- cast
__global__ void cast_kernel(const float* __restrict__ src, bf16* __restrict__ dst, int n4) {
  int i = blockIdx.x * blockDim.x + threadIdx.x;
  if (i >= n4) return;
  float4 v = reinterpret_cast<const float4*>(src)[i];
  union { bf16 h[4]; unsigned long long u; } o;
  o.h[0] = (bf16)v.x; o.h[1] = (bf16)v.y; o.h[2] = (bf16)v.z; o.h[3] = (bf16)v.w;
  reinterpret_cast<unsigned long long*>(dst)[i] = o.u;
}

// ---------------------------------------------------------------- projection
// C[4096,1024] = A[4096,1024] @ W[1024,1024]^T (+bias). 128x128 tile, BK=64.
// proj 0: K -> Kp[b,h,s,64]; proj 1: Q -> Qp[b,h,s,64]; proj 2: V -> Vt[b,h,64,s]
__global__ __launch_bounds__(256) void proj_kernel(
    const bf16* __restrict__ emb, const bf16* __restrict__ qin,
    const bf16* __restrict__ wk, const bf16* __restrict__ wq, const bf16* __restrict__ wv,
    const float* __restrict__ bk, const float* __restrict__ bq, const float* __restrict__ bv,
    bf16* __restrict__ Kp, bf16* __restrict__ Qp, bf16* __restrict__ Vt)
{
  __shared__ bf16 As[128 * 64];
  __shared__ bf16 Bs[128 * 64];

  int pid = blockIdx.x;
  int proj = pid >> 8;       // 0..2
  int t = pid & 255;
  int m0 = (t >> 3) * 128;   // 32 m-tiles
  int n0 = (t & 7) * 128;    // 8 n-tiles

  const bf16* A = (proj == 1) ? qin : emb;
  const bf16* W = (proj == 0) ? wk : (proj == 1) ? wq : wv;
  const float* bias = (proj == 0) ? bk : (proj == 1) ? bq : bv;

  int tid = threadIdx.x;
  int lane = tid & 63, wid = tid >> 6;
  int quad = lane >> 4, l16 = lane & 15;
  int moff = (wid & 1) * 64, noff = (wid >> 1) * 64;

  f32x4 zero = {0.f, 0.f, 0.f, 0.f};
  f32x4 acc[4][4];
#pragma unroll
  for (int i = 0; i < 4; i++)
#pragma unroll
    for (int j = 0; j < 4; j++) acc[i][j] = zero;

  for (int kk = 0; kk < 1024; kk += 64) {
    __syncthreads();
    // stage 128x64 A and B tiles; XOR-swizzle chunk-in-row to avoid bank conflicts
#pragma unroll
    for (int i = 0; i < 4; i++) {
      int c = i * 256 + tid;
      int row = c >> 3;
      int ko = ((c ^ row) & 7) << 3;   // swizzled k-offset (elements)
      async16(&As[(size_t)(i * 256 + wid * 64) * 8], &A[(size_t)(m0 + row) * 1024 + kk + ko]);
      async16(&Bs[(size_t)(i * 256 + wid * 64) * 8], &W[(size_t)(n0 + row) * 1024 + kk + ko]);
    }
    __syncthreads();
#pragma unroll
    for (int ks = 0; ks < 2; ks++) {
      bf16x8 af[4], bfr[4];
#pragma unroll
      for (int i = 0; i < 4; i++) {
        int row = moff + i * 16 + l16;
        af[i] = *reinterpret_cast<const bf16x8*>(&As[row * 64 + ((((ks << 2) | quad) ^ row) & 7) * 8]);
      }
#pragma unroll
      for (int j = 0; j < 4; j++) {
        int row = noff + j * 16 + l16;
        bfr[j] = *reinterpret_cast<const bf16x8*>(&Bs[row * 64 + ((((ks << 2) | quad) ^ row) & 7) * 8]);
      }
#pragma unroll
      for (int i = 0; i < 4; i++)
#pragma unroll
        for (int j = 0; j < 4; j++)
          acc[i][j] = __builtin_amdgcn_mfma_f32_16x16x32_bf16(af[i], bfr[j], acc[i][j], 0, 0, 0);
    }
  }

  float bvv[4];
#pragma unroll
  for (int j = 0; j < 4; j++) bvv[j] = bias[n0 + noff + j * 16 + l16];

  // C/D layout: col = lane&15, row = quad*4 + reg (verified m89/m91)
#pragma unroll
  for (int i = 0; i < 4; i++) {
#pragma unroll
    for (int r = 0; r < 4; r++) {
      int grow = m0 + moff + i * 16 + quad * 4 + r;  // 0..4095
      int bb = grow >> 11;
      int ss = grow & 2047;
#pragma unroll
      for (int j = 0; j < 4; j++) {
        int gcol = n0 + noff + j * 16 + l16;         // 0..1023
        int hh = gcol >> 6, dd = gcol & 63;
        int bh = bb * 16 + hh;
        float v = acc[i][j][r] + bvv[j];
        if (proj == 2) {
          Vt[((size_t)bh * 64 + dd) * 2048 + ss] = (bf16)v;
        } else if (proj == 0) {
          Kp[((size_t)bh * 2048 + ss) * 64 + dd] = (bf16)v;
        } else {
          Qp[((size_t)bh * 2048 + ss) * 64 + dd] = (bf16)v;
        }
      }
    }
  }
}

// ---------------------------------------------------------------- attention
// One block per (bh, 128-row Q tile). 4 waves; wave w owns q-rows [w*32, w*32+32).
__global__ __launch_bounds__(256, 2) void attn_kernel(
    const bf16* __restrict__ Qp, const bf16* __restrict__ Kp, const bf16* __restrict__ Vt,
    float* __restrict__ out)
{
  __shared__ bf16 Qs[128 * 64];
  __shared__ bf16 Ks[128 * 64];
  __shared__ bf16 Vs[64 * 128];   // V^T tile: [d][key]
  __shared__ bf16 Ps[128 * 128];  // P round-trip (swizzled)

  int bid = blockIdx.x;
  int bh = bid >> 4;
  int q0 = (bid & 15) << 7;
  int bb = bh >> 4, hh = bh & 15;

  const bf16* Qg = Qp + (size_t)bh * (2048 * 64);
  const bf16* Kg = Kp + (size_t)bh * (2048 * 64);
  const bf16* Vg = Vt + (size_t)bh * (64 * 2048);

  int tid = threadIdx.x, lane = tid & 63, wid = tid >> 6;
  int quad = lane >> 4, l16 = lane & 15;

  // stage Q tile once
#pragma unroll
  for (int i = 0; i < 4; i++) {
    int c = i * 256 + tid;
    int row = c >> 3;
    int ko = ((c ^ row) & 7) << 3;
    async16(&Qs[(size_t)(i * 256 + wid * 64) * 8], &Qg[(size_t)(q0 + row) * 64 + ko]);
  }

  f32x4 zero = {0.f, 0.f, 0.f, 0.f};
  f32x4 O[2][4];
#pragma unroll
  for (int rt = 0; rt < 2; rt++)
#pragma unroll
    for (int nt = 0; nt < 4; nt++) O[rt][nt] = zero;
  float m_i[2][4], l_i[2][4];
#pragma unroll
  for (int rt = 0; rt < 2; rt++)
#pragma unroll
    for (int r = 0; r < 4; r++) { m_i[rt][r] = -1e30f; l_i[rt][r] = 0.f; }

  bf16x8 qf[2][2];

  for (int kt = 0; kt < 16; kt++) {
    __syncthreads();  // prior iter done reading Ks/Vs
#pragma unroll
    for (int i = 0; i < 4; i++) {
      int c = i * 256 + tid;
      int rk = c >> 3;
      int ko = ((c ^ rk) & 7) << 3;
      async16(&Ks[(size_t)(i * 256 + wid * 64) * 8], &Kg[(size_t)(kt * 128 + rk) * 64 + ko]);
      int rv = c >> 4;
      int so = (((c & 15) ^ rv) & 15) << 3;
      async16(&Vs[(size_t)(i * 256 + wid * 64) * 8], &Vg[(size_t)rv * 2048 + kt * 128 + so]);
    }
    __syncthreads();  // staging complete (vmcnt(0) before barrier)

    if (kt == 0) {
#pragma unroll
      for (int rt = 0; rt < 2; rt++)
#pragma unroll
        for (int ks = 0; ks < 2; ks++) {
          int row = wid * 32 + rt * 16 + l16;
          qf[rt][ks] = *reinterpret_cast<const bf16x8*>(&Qs[row * 64 + ((((ks << 2) | quad) ^ row) & 7) * 8]);
        }
    }

    // scores: wave's 32 q-rows x 128 keys
    f32x4 Sf[8][2];
#pragma unroll
    for (int n = 0; n < 8; n++) {
      int row = n * 16 + l16;
      bf16x8 kf0 = *reinterpret_cast<const bf16x8*>(&Ks[row * 64 + ((quad ^ row) & 7) * 8]);
      bf16x8 kf1 = *reinterpret_cast<const bf16x8*>(&Ks[row * 64 + (((4 | quad) ^ row) & 7) * 8]);
#pragma unroll
      for (int rt = 0; rt < 2; rt++) {
        f32x4 s = zero;
        s = __builtin_amdgcn_mfma_f32_16x16x32_bf16(qf[rt][0], kf0, s, 0, 0, 0);
        s = __builtin_amdgcn_mfma_f32_16x16x32_bf16(qf[rt][1], kf1, s, 0, 0, 0);
        Sf[n][rt] = s;
      }
    }

    // online softmax; scale 1/8 folded into exp argument (max is monotonic)
#pragma unroll
    for (int rt = 0; rt < 2; rt++) {
      float alpha[4];
#pragma unroll
      for (int r = 0; r < 4; r++) {
        float mx = Sf[0][rt][r];
#pragma unroll
        for (int n = 1; n < 8; n++) mx = fmaxf(mx, Sf[n][rt][r]);
        mx = fmaxf(mx, __shfl_xor(mx, 1));
        mx = fmaxf(mx, __shfl_xor(mx, 2));
        mx = fmaxf(mx, __shfl_xor(mx, 4));
        mx = fmaxf(mx, __shfl_xor(mx, 8));
        float mnew = fmaxf(m_i[rt][r], mx);
        float a = __expf((m_i[rt][r] - mnew) * 0.125f);
        m_i[rt][r] = mnew;
        float rs = 0.f;
#pragma unroll
        for (int n = 0; n < 8; n++) {
          float p = __expf((Sf[n][rt][r] - mnew) * 0.125f);
          Sf[n][rt][r] = p;
          rs += p;
        }
        rs += __shfl_xor(rs, 1);
        rs += __shfl_xor(rs, 2);
        rs += __shfl_xor(rs, 4);
        rs += __shfl_xor(rs, 8);
        l_i[rt][r] = l_i[rt][r] * a + rs;
        alpha[r] = a;
      }
      // P -> LDS (bf16, chunk-swizzled); wave reads back only its own rows
      int prow_base = wid * 32 + rt * 16 + quad * 4;
#pragma unroll
      for (int n = 0; n < 8; n++) {
        int colbase = n * 16 + l16;
        int pc = colbase >> 3;
#pragma unroll
        for (int r = 0; r < 4; r++) {
          int prow = prow_base + r;
          Ps[prow * 128 + (((pc ^ prow) & 15) << 3) + (colbase & 7)] = (bf16)Sf[n][rt][r];
        }
      }
      // rescale O before accumulating new PV
#pragma unroll
      for (int nt = 0; nt < 4; nt++)
#pragma unroll
        for (int r = 0; r < 4; r++) O[rt][nt][r] *= alpha[r];
    }

    // PV: O[32 x 64] += P[32 x 128] @ V[128 x 64]
#pragma unroll
    for (int ks = 0; ks < 4; ks++) {
      bf16x8 pf[2];
#pragma unroll
      for (int rt = 0; rt < 2; rt++) {
        int row = wid * 32 + rt * 16 + l16;
        pf[rt] = *reinterpret_cast<const bf16x8*>(&Ps[row * 128 + (((((ks << 2) | quad) ^ row) & 15) << 3)]);
      }
#pragma unroll
      for (int nt = 0; nt < 4; nt++) {
        int rowv = nt * 16 + l16;
        bf16x8 vf = *reinterpret_cast<const bf16x8*>(&Vs[rowv * 128 + (((((ks << 2) | quad) ^ rowv) & 15) << 3)]);
        O[0][nt] = __builtin_amdgcn_mfma_f32_16x16x32_bf16(pf[0], vf, O[0][nt], 0, 0, 0);
        O[1][nt] = __builtin_amdgcn_mfma_f32_16x16x32_bf16(pf[1], vf, O[1][nt], 0, 0, 0);
      }
    }
  }

  // epilogue: out[b][s][h*64+d] fp32
#pragma unroll
  for (int rt = 0; rt < 2; rt++)
#pragma unroll
    for (int r = 0; r < 4; r++) {
      float inv = 1.0f / l_i[rt][r];
      int qrow = q0 + wid * 32 + rt * 16 + quad * 4 + r;
      float* dst = out + ((size_t)bb * 2048 + qrow) * 1024 + hh * 64;
#pragma unroll
      for (int nt = 0; nt < 4; nt++)
        dst[nt * 16 + l16] = O[rt][nt][r] * inv;
    }
}

// ---------------------------------------------------------------- launch
extern "C" void kernel_launch(void* const* d_in, const int* in_sizes, int n_in,
                              void* d_out, int out_size, void* d_ws, size_t ws_size,
                              hipStream_t stream) {
  (void)in_sizes; (void)n_in; (void)out_size; (void)ws_size;
  const float* embed = (const float*)d_in[0];
  const float* qin   = (const float*)d_in[1];
  const float* Wk    = (const float*)d_in[2];
  const float* bk    = (const float*)d_in[3];
  const float* Wq    = (const float*)d_in[4];
  const float* bq    = (const float*)d_in[5];
  const float* Wv    = (const float*)d_in[6];
  const float* bv    = (const float*)d_in[7];
  float* out = (float*)d_out;

  bf16* ws = (bf16*)d_ws;
  bf16* emb_bf = ws;                       // 4,194,304
  bf16* q_bf   = emb_bf + 4194304;         // 4,194,304
  bf16* wk_bf  = q_bf   + 4194304;         // 1,048,576
  bf16* wq_bf  = wk_bf  + 1048576;
  bf16* wv_bf  = wq_bf  + 1048576;
  bf16* Kp     = wv_bf  + 1048576;         // 4,194,304  [b,h,s,64]
  bf16* Qp     = Kp     + 4194304;         // 4,194,304  [b,h,s,64]
  bf16* Vt     = Qp     + 4194304;         // 4,194,304  [b,h,64,s]
  // total 24,117,248 bf16 = 48.2 MB of workspace

  cast_kernel<<<4096, 256, 0, stream>>>(embed, emb_bf, 1048576);
  cast_kernel<<<4096, 256, 0, stream>>>(qin,   q_bf,   1048576);
  cast_kernel<<<1024, 256, 0, stream>>>(Wk,    wk_bf,  262144);
  cast_kernel<<<1024, 256, 0, stream>>>(Wq,    wq_bf,  262144);
  cast_kernel<<<1024, 256, 0, stream>>>(Wv,    wv_bf,  262144);

  proj_kernel<<<768, 256, 0, stream>>>(emb_bf, q_bf, wk_bf, wq_bf, wv_bf,
                                       bk, bq, bv, Kp, Qp, Vt);
  attn_kernel<<<512, 256, 0, stream>>>(Qp, Kp, Vt, out);
}

// Round 3
// 199.784 us; speedup vs baseline: 1.2803x; 1.2803x over previous
//
#include <hip/hip_runtime.h>
#include <cstdint>
#include <cstddef>

// CrossMultiheadAttention: B=2, S=2048, E=1024, NHEAD=16, HEAD=64
// cast fp32->bf16 (fused) -> MFMA QKV projection (V projection computes C^T so
// V^T stores coalesce) -> flash attention with S^T = K Q^T (lane-local softmax,
// in-register P^T -> mfma_16x16x16 B-operand), double-buffered K/V staging with
// cross-iteration async prefetch (1 barrier/iter).

using bf16 = __bf16;
typedef __bf16 bf16x8 __attribute__((ext_vector_type(8)));
typedef float f32x4 __attribute__((ext_vector_type(4)));
typedef short short4v __attribute__((ext_vector_type(4)));

__device__ __forceinline__ void async16(void* lds, const void* g) {
  __builtin_amdgcn_global_load_lds((__attribute__((address_space(1))) void*)g,
                                   (__attribute__((address_space(3))) void*)lds,
                                   16, 0, 0);
}

__device__ __forceinline__ short bf16_bits(float f) {
  bf16 h = (bf16)f;
  union { bf16 h; short s; } u; u.h = h;
  return u.s;
}

// ---------------------------------------------------------------- fused cast
// segments (float4 units): emb 1048576 | q 1048576 | wk 262144 | wq | wv
__global__ void cast_all_kernel(const float* __restrict__ e, const float* __restrict__ q,
                                const float* __restrict__ wk, const float* __restrict__ wq,
                                const float* __restrict__ wv, bf16* __restrict__ dst) {
  int i = blockIdx.x * blockDim.x + threadIdx.x;
  if (i >= 2883584) return;
  const float* src; int off;
  if (i < 1048576)      { src = e;  off = 0; }
  else if (i < 2097152) { src = q;  off = 1048576; }
  else if (i < 2359296) { src = wk; off = 2097152; }
  else if (i < 2621440) { src = wq; off = 2359296; }
  else                  { src = wv; off = 2621440; }
  float4 v = reinterpret_cast<const float4*>(src)[i - off];
  union { bf16 h[4]; unsigned long long u; } o;
  o.h[0] = (bf16)v.x; o.h[1] = (bf16)v.y; o.h[2] = (bf16)v.z; o.h[3] = (bf16)v.w;
  reinterpret_cast<unsigned long long*>(dst)[i] = o.u;
}

// ---------------------------------------------------------------- projection
// C[4096,1024] = A[4096,1024] @ W[1024,1024]^T (+bias). 128x128 tile, BK=64.
// proj 0: K -> Kp[b,h,s,64]; proj 1: Q -> Qp[b,h,s,64]
// proj 2: computes C^T (swapped MFMA operands) -> Vt[b,h,64,s], coalesced.
__global__ __launch_bounds__(256) void proj_kernel(
    const bf16* __restrict__ emb, const bf16* __restrict__ qin,
    const bf16* __restrict__ wk, const bf16* __restrict__ wq, const bf16* __restrict__ wv,
    const float* __restrict__ bk, const float* __restrict__ bq, const float* __restrict__ bv,
    bf16* __restrict__ Kp, bf16* __restrict__ Qp, bf16* __restrict__ Vt)
{
  __shared__ bf16 As[128 * 64];
  __shared__ bf16 Bs[128 * 64];

  int pid = blockIdx.x;
  int proj = pid >> 8;
  int t = pid & 255;
  int m0 = (t >> 3) * 128;
  int n0 = (t & 7) * 128;

  const bf16* A = (proj == 1) ? qin : emb;
  const bf16* W = (proj == 0) ? wk : (proj == 1) ? wq : wv;
  const float* bias = (proj == 0) ? bk : (proj == 1) ? bq : bv;
  const bool proj2 = (proj == 2);

  int tid = threadIdx.x;
  int lane = tid & 63, wid = tid >> 6;
  int quad = lane >> 4, l16 = lane & 15;
  int moff = (wid & 1) * 64, noff = (wid >> 1) * 64;

  f32x4 zero = {0.f, 0.f, 0.f, 0.f};
  f32x4 acc[4][4];
#pragma unroll
  for (int i = 0; i < 4; i++)
#pragma unroll
    for (int j = 0; j < 4; j++) acc[i][j] = zero;

  for (int kk = 0; kk < 1024; kk += 64) {
    __syncthreads();
#pragma unroll
    for (int i = 0; i < 4; i++) {
      int c = i * 256 + tid;
      int row = c >> 3;
      int ko = ((c ^ row) & 7) << 3;
      async16(&As[(size_t)(i * 256 + wid * 64) * 8], &A[(size_t)(m0 + row) * 1024 + kk + ko]);
      async16(&Bs[(size_t)(i * 256 + wid * 64) * 8], &W[(size_t)(n0 + row) * 1024 + kk + ko]);
    }
    __syncthreads();
#pragma unroll
    for (int ks = 0; ks < 2; ks++) {
      bf16x8 af[4], bfr[4];
#pragma unroll
      for (int i = 0; i < 4; i++) {
        int row = moff + i * 16 + l16;
        af[i] = *reinterpret_cast<const bf16x8*>(&As[row * 64 + ((((ks << 2) | quad) ^ row) & 7) * 8]);
      }
#pragma unroll
      for (int j = 0; j < 4; j++) {
        int row = noff + j * 16 + l16;
        bfr[j] = *reinterpret_cast<const bf16x8*>(&Bs[row * 64 + ((((ks << 2) | quad) ^ row) & 7) * 8]);
      }
      if (proj2) {
#pragma unroll
        for (int i = 0; i < 4; i++)
#pragma unroll
          for (int j = 0; j < 4; j++)
            acc[i][j] = __builtin_amdgcn_mfma_f32_16x16x32_bf16(bfr[j], af[i], acc[i][j], 0, 0, 0);
      } else {
#pragma unroll
        for (int i = 0; i < 4; i++)
#pragma unroll
          for (int j = 0; j < 4; j++)
            acc[i][j] = __builtin_amdgcn_mfma_f32_16x16x32_bf16(af[i], bfr[j], acc[i][j], 0, 0, 0);
      }
    }
  }

  if (proj2) {
    // acc[i][j]: D row = W-row (gcol) = quad*4+r, D col = emb-row (grow) = l16
#pragma unroll
    for (int i = 0; i < 4; i++) {
      int grow = m0 + moff + i * 16 + l16;
      int bb = grow >> 11;
      int ss = grow & 2047;
#pragma unroll
      for (int j = 0; j < 4; j++) {
#pragma unroll
        for (int r = 0; r < 4; r++) {
          int gcol = n0 + noff + j * 16 + quad * 4 + r;
          int hh = gcol >> 6, dd = gcol & 63;
          int bh = bb * 16 + hh;
          float v = acc[i][j][r] + bias[gcol];
          Vt[((size_t)bh * 64 + dd) * 2048 + ss] = (bf16)v;   // lanes -> consecutive ss
        }
      }
    }
  } else {
    float bvv[4];
#pragma unroll
    for (int j = 0; j < 4; j++) bvv[j] = bias[n0 + noff + j * 16 + l16];
    bf16* dst = (proj == 0) ? Kp : Qp;
#pragma unroll
    for (int i = 0; i < 4; i++) {
#pragma unroll
      for (int r = 0; r < 4; r++) {
        int grow = m0 + moff + i * 16 + quad * 4 + r;
        int bb = grow >> 11;
        int ss = grow & 2047;
#pragma unroll
        for (int j = 0; j < 4; j++) {
          int gcol = n0 + noff + j * 16 + l16;
          int hh = gcol >> 6, dd = gcol & 63;
          int bh = bb * 16 + hh;
          float v = acc[i][j][r] + bvv[j];
          dst[((size_t)bh * 2048 + ss) * 64 + dd] = (bf16)v;
        }
      }
    }
  }
}

// ---------------------------------------------------------------- attention
// One block per (bh, 128-query tile). 4 waves; wave w owns queries [w*32, w*32+32).
// S^T = K Q^T so softmax reduces in-lane. Double-buffered K/V staging: prefetch
// tile kt+1 right after the barrier, compute on tile kt. One barrier/iteration.
__global__ __launch_bounds__(256, 2) void attn_kernel(
    const bf16* __restrict__ Qp, const bf16* __restrict__ Kp, const bf16* __restrict__ Vt,
    float* __restrict__ out)
{
  __shared__ bf16 Ks[2][128 * 64];
  __shared__ bf16 Vs[2][64 * 128];   // V^T tile: [d][key]

  int bid = blockIdx.x;
  int bh = bid >> 4;
  int q0 = (bid & 15) << 7;
  int bb = bh >> 4, hh = bh & 15;

  const bf16* Qg = Qp + (size_t)bh * (2048 * 64);
  const bf16* Kg = Kp + (size_t)bh * (2048 * 64);
  const bf16* Vg = Vt + (size_t)bh * (64 * 2048);

  int tid = threadIdx.x, lane = tid & 63, wid = tid >> 6;
  int quad = lane >> 4, l16 = lane & 15;
  int wq0 = q0 + wid * 32;

  auto stage = [&](int kt_, int buf) {
#pragma unroll
    for (int i = 0; i < 4; i++) {
      int c = i * 256 + tid;
      int rk = c >> 3;
      int ko = ((c ^ rk) & 7) << 3;
      async16(&Ks[buf][(size_t)(i * 256 + wid * 64) * 8], &Kg[(size_t)(kt_ * 128 + rk) * 64 + ko]);
      int rv = c >> 4;
      int so = (((c & 15) ^ rv) & 15) << 3;
      async16(&Vs[buf][(size_t)(i * 256 + wid * 64) * 8], &Vg[(size_t)rv * 2048 + kt_ * 128 + so]);
    }
  };

  // Q fragments direct from global (B-operand: n=l16=query, k=quad*8+j per chunk)
  bf16x8 qf[2][2];
#pragma unroll
  for (int qt = 0; qt < 2; qt++)
#pragma unroll
    for (int ks = 0; ks < 2; ks++)
      qf[qt][ks] = *reinterpret_cast<const bf16x8*>(
          &Qg[(size_t)(wq0 + qt * 16 + l16) * 64 + ks * 32 + quad * 8]);

  stage(0, 0);   // pre-stage tile 0 into buffer 0

  f32x4 zero = {0.f, 0.f, 0.f, 0.f};
  f32x4 O[2][4];     // O^T C-tiles: [qt][dtile], row=d(quad*4+r), col=query(l16)
#pragma unroll
  for (int qt = 0; qt < 2; qt++)
#pragma unroll
    for (int dt = 0; dt < 4; dt++) O[qt][dt] = zero;
  float m_i[2] = {-1e30f, -1e30f};
  float l_i[2] = {0.f, 0.f};

  for (int kt = 0; kt < 16; kt++) {
    int cur = kt & 1;
    __syncthreads();                     // staging for buf[cur] complete everywhere
    __builtin_amdgcn_sched_barrier(0);   // pin prefetch below the barrier
    if (kt < 15) stage(kt + 1, cur ^ 1); // async prefetch into the other buffer
    __builtin_amdgcn_sched_barrier(0);

    const bf16* Kc = Ks[cur];
    const bf16* Vc = Vs[cur];

    // S^T scores: Sf[qt][n], row = key (n*16 + quad*4 + r), col = query (l16)
    f32x4 Sf[2][8];
#pragma unroll
    for (int n = 0; n < 8; n++) {
      int row = n * 16 + l16;   // key row: A-operand lane m = l16
      bf16x8 kf0 = *reinterpret_cast<const bf16x8*>(&Kc[row * 64 + ((quad ^ row) & 7) * 8]);
      bf16x8 kf1 = *reinterpret_cast<const bf16x8*>(&Kc[row * 64 + (((4 | quad) ^ row) & 7) * 8]);
#pragma unroll
      for (int qt = 0; qt < 2; qt++) {
        f32x4 s = zero;
        s = __builtin_amdgcn_mfma_f32_16x16x32_bf16(kf0, qf[qt][0], s, 0, 0, 0);
        s = __builtin_amdgcn_mfma_f32_16x16x32_bf16(kf1, qf[qt][1], s, 0, 0, 0);
        Sf[qt][n] = s;
      }
    }

    // online softmax per query column: in-lane over 32 keys + 2 quad shuffles
#pragma unroll
    for (int qt = 0; qt < 2; qt++) {
      float mx = -1e30f;
#pragma unroll
      for (int n = 0; n < 8; n++)
#pragma unroll
        for (int r = 0; r < 4; r++) mx = fmaxf(mx, Sf[qt][n][r]);
      mx = fmaxf(mx, __shfl_xor(mx, 16));
      mx = fmaxf(mx, __shfl_xor(mx, 32));
      float mnew = fmaxf(m_i[qt], mx);
      float a = __expf((m_i[qt] - mnew) * 0.125f);
      m_i[qt] = mnew;
      float rs = 0.f;
#pragma unroll
      for (int n = 0; n < 8; n++)
#pragma unroll
        for (int r = 0; r < 4; r++) {
          float p = __expf((Sf[qt][n][r] - mnew) * 0.125f);
          Sf[qt][n][r] = p;
          rs += p;
        }
      rs += __shfl_xor(rs, 16);
      rs += __shfl_xor(rs, 32);
      l_i[qt] = l_i[qt] * a + rs;
#pragma unroll
      for (int dt = 0; dt < 4; dt++)
#pragma unroll
        for (int r = 0; r < 4; r++) O[qt][dt][r] *= a;
    }

    // PV: O^T[d][q] += V^T[d][k] * P^T[k][q] via mfma_16x16x16 (K=16 per n)
#pragma unroll
    for (int n = 0; n < 8; n++) {
      short4v pf[2];
#pragma unroll
      for (int qt = 0; qt < 2; qt++) {
        union { short s[4]; short4v v; } u;
#pragma unroll
        for (int r = 0; r < 4; r++) u.s[r] = bf16_bits(Sf[qt][n][r]);
        pf[qt] = u.v;
      }
      int cj = n * 2 + (quad >> 1);
      int sub = (quad & 1) * 4;
#pragma unroll
      for (int dt = 0; dt < 4; dt++) {
        int rowv = dt * 16 + l16;
        short4v vf = *reinterpret_cast<const short4v*>(
            &Vc[rowv * 128 + (((cj ^ rowv) & 15) << 3) + sub]);
        O[0][dt] = __builtin_amdgcn_mfma_f32_16x16x16bf16_1k(vf, pf[0], O[0][dt], 0, 0, 0);
        O[1][dt] = __builtin_amdgcn_mfma_f32_16x16x16bf16_1k(vf, pf[1], O[1][dt], 0, 0, 0);
      }
    }
  }

  // epilogue: lane holds 4 consecutive d per tile -> float4 stores
#pragma unroll
  for (int qt = 0; qt < 2; qt++) {
    float inv = 1.0f / l_i[qt];
    int qrow = wq0 + qt * 16 + l16;
    float* dst = out + ((size_t)bb * 2048 + qrow) * 1024 + hh * 64;
#pragma unroll
    for (int dt = 0; dt < 4; dt++) {
      float4 o;
      o.x = O[qt][dt][0] * inv;
      o.y = O[qt][dt][1] * inv;
      o.z = O[qt][dt][2] * inv;
      o.w = O[qt][dt][3] * inv;
      *reinterpret_cast<float4*>(&dst[dt * 16 + quad * 4]) = o;
    }
  }
}

// ---------------------------------------------------------------- launch
extern "C" void kernel_launch(void* const* d_in, const int* in_sizes, int n_in,
                              void* d_out, int out_size, void* d_ws, size_t ws_size,
                              hipStream_t stream) {
  (void)in_sizes; (void)n_in; (void)out_size; (void)ws_size;
  const float* embed = (const float*)d_in[0];
  const float* qin   = (const float*)d_in[1];
  const float* Wk    = (const float*)d_in[2];
  const float* bk    = (const float*)d_in[3];
  const float* Wq    = (const float*)d_in[4];
  const float* bq    = (const float*)d_in[5];
  const float* Wv    = (const float*)d_in[6];
  const float* bv    = (const float*)d_in[7];
  float* out = (float*)d_out;

  bf16* ws = (bf16*)d_ws;
  bf16* emb_bf = ws;                       // 4,194,304
  bf16* q_bf   = emb_bf + 4194304;         // 4,194,304
  bf16* wk_bf  = q_bf   + 4194304;         // 1,048,576
  bf16* wq_bf  = wk_bf  + 1048576;
  bf16* wv_bf  = wq_bf  + 1048576;
  bf16* Kp     = wv_bf  + 1048576;         // [b,h,s,64]
  bf16* Qp     = Kp     + 4194304;         // [b,h,s,64]
  bf16* Vt     = Qp     + 4194304;         // [b,h,64,s]

  cast_all_kernel<<<11264, 256, 0, stream>>>(embed, qin, Wk, Wq, Wv, ws);

  proj_kernel<<<768, 256, 0, stream>>>(emb_bf, q_bf, wk_bf, wq_bf, wv_bf,
                                       bk, bq, bv, Kp, Qp, Vt);
  attn_kernel<<<512, 256, 0, stream>>>(Qp, Kp, Vt, out);
}